// Round 1
// baseline (77.824 us; speedup 1.0000x reference)
//
#include <hip/hip_runtime.h>

// Problem constants (fixed by setup_inputs): x(64,32768,6) f32, templates(16,6,80), delays(16,6)
#define BB 64
#define SS 32768
#define FF 6
#define EE 16
#define LL 80
#define KK 480      // F*L
#define NSL 15      // K / 32
#define TBLK 128    // time positions per block
#define NPHI 8      // phase copies (t = t0 + phi + 8*row)
#define WROW 208    // padded LDS window row (200 needed)
#define WLDST 488   // Wlds row stride in elems (bank-spread, 16B-aligned)

typedef _Float16 half8 __attribute__((ext_vector_type(8)));
typedef float f32x4 __attribute__((ext_vector_type(4)));

struct __align__(4) hpair { _Float16 a, b; };

// Build reversed, delay-shifted kernel: wrev[e*480 + f*80 + r] = delayed[e,f,79-r]
__global__ void prep_kernel(const float* __restrict__ tpl, const float* __restrict__ dly,
                            _Float16* __restrict__ wrev) {
    int n = blockIdx.x * 256 + threadIdx.x;
    if (n >= EE * KK) return;
    int e = n / KK, k = n - e * KK;
    int f = k / LL, r = k - f * LL;
    int m = LL - 1 - r;
    float dl = fminf(fmaxf(dly[e * FF + f], -10.f), 10.f);
    int d = (int)rintf(dl);                 // RNE, matches jnp.round
    int src = m - d;
    float v = (src >= 0 && src < LL) ? tpl[(e * FF + f) * LL + src] : 0.f;
    wrev[n] = (_Float16)v;                  // NOT pre-scaled (avoid f16 denormals)
}

template <bool FROM_WS>
__global__ __launch_bounds__(512, 4) void corr_kernel(
    const float* __restrict__ x, const float* __restrict__ tpl,
    const float* __restrict__ dly, const _Float16* __restrict__ wrev,
    float* __restrict__ out) {
    __shared__ alignas(16) _Float16 Wlds[EE * WLDST];        // 15,616 B
    __shared__ alignas(16) _Float16 xs[NPHI][FF][WROW];      // 19,968 B

    int tid = threadIdx.x;
    int b = blockIdx.x >> 8;              // 256 t-blocks per batch
    int t0 = (blockIdx.x & 255) << 7;     // *128

    // ---- weights into LDS ----
    if (FROM_WS) {
        for (int gi = tid; gi < EE * KK / 8; gi += 512) {    // 960 groups of 8
            int e = gi / 60;
            int k8 = (gi - e * 60) * 8;
            *(uint4*)&Wlds[e * WLDST + k8] = *(const uint4*)&wrev[e * KK + k8];
        }
    } else {
        for (int n = tid; n < EE * KK; n += 512) {
            int e = n / KK, k = n - e * KK;
            int f = k / LL, r = k - f * LL;
            int m = LL - 1 - r;
            float dl = fminf(fmaxf(dly[e * FF + f], -10.f), 10.f);
            int d = (int)rintf(dl);
            int src = m - d;
            float v = (src >= 0 && src < LL) ? tpl[(e * FF + f) * LL + src] : 0.f;
            Wlds[e * WLDST + k] = (_Float16)v;
        }
    }

    // ---- stage x: 8 phase copies, copy phi covers positions [t0+phi-39, t0+phi+161) ----
    const float* xb = x + (size_t)b * (SS * FF);
    for (int it = tid; it < NPHI * 100; it += 512) {   // pairs of positions
        int phi = it / 100;
        int i = (it - phi * 100) * 2;
        int pos = t0 + phi - 39 + i;
        float va[12];
        if (pos >= 0 && pos <= SS - 2) {
            const float* xp = xb + (size_t)pos * FF;   // 12 contiguous floats
            #pragma unroll
            for (int q = 0; q < 6; q++)
                *(float2*)&va[2 * q] = *(const float2*)&xp[2 * q];
        } else {
            #pragma unroll
            for (int q = 0; q < 2; q++) {
                int p = pos + q;
                bool ok = (p >= 0) && (p < SS);
                #pragma unroll
                for (int f = 0; f < FF; f++)
                    va[q * 6 + f] = ok ? xb[(size_t)p * FF + f] : 0.f;
            }
        }
        #pragma unroll
        for (int f = 0; f < FF; f++) {
            hpair hp;
            hp.a = (_Float16)va[f];
            hp.b = (_Float16)va[6 + f];
            *(hpair*)&xs[phi][f][i] = hp;   // i even -> 4B aligned
        }
    }
    __syncthreads();

    int lane = tid & 63;
    int wid = tid >> 6;          // 8 waves = 8 phases
    int e = lane & 15;
    int g = lane >> 4;

    // B fragments: 15 slices resident in registers (60 VGPRs)
    half8 bq[NSL];
    #pragma unroll
    for (int s = 0; s < NSL; s++)
        bq[s] = *(const half8*)&Wlds[e * WLDST + 32 * s + 8 * g];

    int phi = wid;
    f32x4 acc = {0.f, 0.f, 0.f, 0.f};
    int row16 = 8 * (lane & 15);   // A-row (l&15) at t-stride 8 -> elem offset 8*(l&15)
    #pragma unroll
    for (int s = 0; s < NSL; s++) {
        int k0 = 32 * s + 8 * g;
        int f = (k0 * 205) >> 14;        // exact k0/80 for k0 in [0,480)
        int r0 = k0 - 80 * f;
        const half8 a = *(const half8*)&xs[phi][f][row16 + r0];  // 16B aligned ds_read_b128
        acc = __builtin_amdgcn_mfma_f32_16x16x32_f16(a, bq[s], acc, 0, 0, 0);
    }

    // D layout: row = g*4 + j, col = e ; t = t0 + phi + 8*row
    #pragma unroll
    for (int j = 0; j < 4; j++) {
        int row = g * 4 + j;
        int t = t0 + phi + 8 * row;
        float v = acc[j] * (1.0f / 480.0f);
        if (t == SS - 1) v = 0.f;        // reference zero-pads the last position
        out[((size_t)b * SS + t) * EE + e] = v;
    }
}

extern "C" void kernel_launch(void* const* d_in, const int* in_sizes, int n_in,
                              void* d_out, int out_size, void* d_ws, size_t ws_size,
                              hipStream_t stream) {
    const float* x = (const float*)d_in[0];
    const float* tpl = (const float*)d_in[1];
    const float* dly = (const float*)d_in[2];
    float* out = (float*)d_out;

    int grid = BB * (SS / TBLK);   // 16384 blocks, 512 threads (8 waves)
    if (ws_size >= (size_t)(EE * KK * sizeof(_Float16))) {
        _Float16* wrev = (_Float16*)d_ws;
        prep_kernel<<<(EE * KK + 255) / 256, 256, 0, stream>>>(tpl, dly, wrev);
        corr_kernel<true><<<grid, 512, 0, stream>>>(x, tpl, dly, wrev, out);
    } else {
        corr_kernel<false><<<grid, 512, 0, stream>>>(x, tpl, dly, nullptr, out);
    }
}

// Round 2
// 66.976 us; speedup vs baseline: 1.1620x; 1.1620x over previous
//
#include <hip/hip_runtime.h>

// Problem constants (fixed by setup_inputs): x(64,32768,6) f32, templates(16,6,80), delays(16,6)
#define BB 64
#define SS 32768
#define FF 6
#define EE 16
#define LL 80
#define KK 480      // F*L
#define NSL 15      // K / 32
#define TBLK 256    // time positions per block
#define NPHI 4      // phase copies (t = t0 + phi + 4*row)
#define ROWS 64     // rows per phase = TBLK/NPHI
#define WROW 336    // xs row stride in elems (needs >= 332)
#define WUNITS 166  // position-pairs staged per copy (332 positions)
#define WLDST 488   // Wlds row stride in elems (16B-aligned)

typedef _Float16 half8 __attribute__((ext_vector_type(8)));
typedef float f32x4 __attribute__((ext_vector_type(4)));

// Build reversed, delay-shifted kernel: wrev[e*480 + f*80 + r] = delayed[e,f,79-r]
__global__ void prep_kernel(const float* __restrict__ tpl, const float* __restrict__ dly,
                            _Float16* __restrict__ wrev) {
    int n = blockIdx.x * 256 + threadIdx.x;
    if (n >= EE * KK) return;
    int e = n / KK, k = n - e * KK;
    int f = k / LL, r = k - f * LL;
    int m = LL - 1 - r;
    float dl = fminf(fmaxf(dly[e * FF + f], -10.f), 10.f);
    int d = (int)rintf(dl);                 // RNE, matches jnp.round
    int src = m - d;
    float v = (src >= 0 && src < LL) ? tpl[(e * FF + f) * LL + src] : 0.f;
    wrev[n] = (_Float16)v;                  // NOT pre-scaled (avoid f16 denormals)
}

template <bool FROM_WS>
__global__ __launch_bounds__(512, 4) void corr_kernel(
    const float* __restrict__ x, const float* __restrict__ tpl,
    const float* __restrict__ dly, const _Float16* __restrict__ wrev,
    float* __restrict__ out) {
    __shared__ alignas(16) _Float16 Wlds[EE * WLDST];        // 15,616 B
    __shared__ alignas(16) _Float16 xs[NPHI][FF][WROW];      // 16,128 B

    int tid = threadIdx.x;
    int b = blockIdx.x >> 7;              // 128 t-blocks per batch
    int t0 = (blockIdx.x & 127) << 8;     // *256

    // ---- weights into LDS ----
    if (FROM_WS) {
        for (int gi = tid; gi < EE * KK / 8; gi += 512) {    // 960 groups of 8
            int e = gi / 60;
            int k8 = (gi - e * 60) * 8;
            *(uint4*)&Wlds[e * WLDST + k8] = *(const uint4*)&wrev[e * KK + k8];
        }
    } else {
        for (int n = tid; n < EE * KK; n += 512) {
            int e = n / KK, k = n - e * KK;
            int f = k / LL, r = k - f * LL;
            int m = LL - 1 - r;
            float dl = fminf(fmaxf(dly[e * FF + f], -10.f), 10.f);
            int d = (int)rintf(dl);
            int src = m - d;
            float v = (src >= 0 && src < LL) ? tpl[(e * FF + f) * LL + src] : 0.f;
            Wlds[e * WLDST + k] = (_Float16)v;
        }
    }

    // ---- stage x: 4 phase copies, copy phi covers positions [t0+phi-39, t0+phi+293) ----
    const float* xb = x + (size_t)b * (SS * FF);
    for (int it = tid; it < NPHI * WUNITS; it += 512) {   // pairs of positions
        int phi = it / WUNITS;
        int i = (it - phi * WUNITS) * 2;
        int pos = t0 + phi - 39 + i;
        float va[12];
        if (pos >= 0 && pos <= SS - 2) {
            const float* xp = xb + (size_t)pos * FF;   // 12 contiguous floats, 8B-aligned
            #pragma unroll
            for (int q = 0; q < 6; q++)
                *(float2*)&va[2 * q] = *(const float2*)&xp[2 * q];
        } else {
            #pragma unroll
            for (int q = 0; q < 2; q++) {
                int p = pos + q;
                bool ok = (p >= 0) && (p < SS);
                #pragma unroll
                for (int f = 0; f < FF; f++)
                    va[q * 6 + f] = ok ? xb[(size_t)p * FF + f] : 0.f;
            }
        }
        #pragma unroll
        for (int f = 0; f < FF; f++) {
#if __has_builtin(__builtin_amdgcn_cvt_pkrtz)
            __fp16 __attribute__((ext_vector_type(2))) hp =
                __builtin_amdgcn_cvt_pkrtz(va[f], va[6 + f]);
            *(decltype(hp)*)&xs[phi][f][i] = hp;      // i even -> 4B aligned
#else
            xs[phi][f][i] = (_Float16)va[f];
            xs[phi][f][i + 1] = (_Float16)va[6 + f];
#endif
        }
    }
    __syncthreads();

    int lane = tid & 63;
    int wid = tid >> 6;
    int e = lane & 15;
    int g = lane >> 4;
    int phi = wid & 3;          // 4 phases
    int pairi = wid >> 2;       // 2 row-halves per phase

    // B fragments: 15 slices resident in registers
    half8 bq[NSL];
    #pragma unroll
    for (int s = 0; s < NSL; s++)
        bq[s] = *(const half8*)&Wlds[e * WLDST + 32 * s + 8 * g];

    const char* xph = (const char*)&xs[phi][0][0];
    f32x4 acc[2];
    #pragma unroll
    for (int tt = 0; tt < 2; tt++) acc[tt] = (f32x4){0.f, 0.f, 0.f, 0.f};

    #pragma unroll
    for (int tt = 0; tt < 2; tt++) {
        int R = pairi * 32 + tt * 16 + (lane & 15);    // A-row position index (t-stride 4)
        #pragma unroll
        for (int s = 0; s < NSL; s++) {
            int k0 = 32 * s + 8 * g;
            int f = (k0 * 205) >> 14;        // exact k0/80 for k0 in [0,480)
            int r0 = k0 - 80 * f;
            const char* p = xph + 2 * (f * WROW + 4 * R + r0);   // 8B-aligned
            uint2 lo = *(const uint2*)p;
            uint2 hi = *(const uint2*)(p + 8);
            union { unsigned u[4]; half8 h; } av;
            av.u[0] = lo.x; av.u[1] = lo.y; av.u[2] = hi.x; av.u[3] = hi.y;
            acc[tt] = __builtin_amdgcn_mfma_f32_16x16x32_f16(av.h, bq[s], acc[tt], 0, 0, 0);
        }
    }

    // D layout: row = g*4 + j, col = e ; t = t0 + phi + 4*(tilebase + row)
    #pragma unroll
    for (int tt = 0; tt < 2; tt++) {
        #pragma unroll
        for (int j = 0; j < 4; j++) {
            int row = pairi * 32 + tt * 16 + g * 4 + j;
            int t = t0 + phi + 4 * row;
            float v = acc[tt][j] * (1.0f / 480.0f);
            if (t == SS - 1) v = 0.f;        // reference zero-pads the last position
            out[((size_t)b * SS + t) * EE + e] = v;
        }
    }
}

extern "C" void kernel_launch(void* const* d_in, const int* in_sizes, int n_in,
                              void* d_out, int out_size, void* d_ws, size_t ws_size,
                              hipStream_t stream) {
    const float* x = (const float*)d_in[0];
    const float* tpl = (const float*)d_in[1];
    const float* dly = (const float*)d_in[2];
    float* out = (float*)d_out;

    int grid = BB * (SS / TBLK);   // 8192 blocks, 512 threads (8 waves)
    if (ws_size >= (size_t)(EE * KK * sizeof(_Float16))) {
        _Float16* wrev = (_Float16*)d_ws;
        prep_kernel<<<(EE * KK + 255) / 256, 256, 0, stream>>>(tpl, dly, wrev);
        corr_kernel<true><<<grid, 512, 0, stream>>>(x, tpl, dly, wrev, out);
    } else {
        corr_kernel<false><<<grid, 512, 0, stream>>>(x, tpl, dly, nullptr, out);
    }
}